// Round 1
// baseline (219.294 us; speedup 1.0000x reference)
//
#include <hip/hip_runtime.h>

// out[b,h,w,c] = t1*w0[c] + t2*w1[c] + t3*w2[c]
// N = 16*128*128*256 = 67,108,864 fp32 elems; memory-bound streaming op.
// float4 path: n4 = N/4 = 16,777,216 vectors. Grid-stride with stride a
// multiple of 64 float4s keeps each thread's channel quad fixed -> weights
// hoisted to 12 registers, loaded once per thread (3 KB table, L1-resident).

__global__ __launch_bounds__(256) void merge3_kernel(
    const float4* __restrict__ t1,
    const float4* __restrict__ t2,
    const float4* __restrict__ t3,
    const float*  __restrict__ weights,   // (C=256, 3) row-major
    float4* __restrict__ out,
    int n4)
{
    const int tid    = blockIdx.x * blockDim.x + threadIdx.x;
    const int stride = gridDim.x * blockDim.x;   // multiple of 256 -> mult of 64

    // Fixed channel quad for this thread across all grid-stride iterations:
    // element index of float4 i is 4*i; channel = (4*i) % 256.
    const int cbase = (tid & 63) * 4;
    float w0[4], w1[4], w2[4];
    #pragma unroll
    for (int k = 0; k < 4; ++k) {
        w0[k] = weights[(cbase + k) * 3 + 0];
        w1[k] = weights[(cbase + k) * 3 + 1];
        w2[k] = weights[(cbase + k) * 3 + 2];
    }

    for (int i = tid; i < n4; i += stride) {
        float4 a = t1[i];
        float4 b = t2[i];
        float4 c = t3[i];
        float4 o;
        o.x = fmaf(a.x, w0[0], fmaf(b.x, w1[0], c.x * w2[0]));
        o.y = fmaf(a.y, w0[1], fmaf(b.y, w1[1], c.y * w2[1]));
        o.z = fmaf(a.z, w0[2], fmaf(b.z, w1[2], c.z * w2[2]));
        o.w = fmaf(a.w, w0[3], fmaf(b.w, w1[3], c.w * w2[3]));
        out[i] = o;
    }
}

extern "C" void kernel_launch(void* const* d_in, const int* in_sizes, int n_in,
                              void* d_out, int out_size, void* d_ws, size_t ws_size,
                              hipStream_t stream) {
    const float4* t1 = (const float4*)d_in[0];
    const float4* t2 = (const float4*)d_in[1];
    const float4* t3 = (const float4*)d_in[2];
    const float*  w  = (const float*)d_in[3];
    float4* out = (float4*)d_out;

    const int n4 = out_size / 4;   // 16,777,216

    // 2048 blocks x 256 threads = 8192 waves = full chip wave capacity
    // (256 CU x 32 waves/CU); each thread does 32 float4 iterations.
    dim3 grid(2048), block(256);
    merge3_kernel<<<grid, block, 0, stream>>>(t1, t2, t3, w, out, n4);
}